// Round 1
// baseline (334.119 us; speedup 1.0000x reference)
//
#include <hip/hip_runtime.h>

// SNN leaky integrate-and-fire, fused matvec + 255-step recurrence.
// x: [65536, 784] f32, W: [1, 784] f32.
// out = concat(spk_rec [255,65536], mem_rec [255,65536]) f32.
//
// Strategy: 1-wave (64-thread) blocks, each block owns 64 consecutive rows.
// Phase 1: wave-cooperative dot product per row (coalesced float4 loads,
//          f64 accumulation, shuffle tree-reduce) -> LDS.
// Phase 2: thread-per-row recurrence in f64 (exact math vs chaotic reset
//          threshold), coalesced f32 stores per step.

#define NROWS   65536
#define DIM     784            // = 196 float4
#define STEPS   255
#define BETA    0.95
#define ROWS_PB 64

__global__ __launch_bounds__(64) void snn_fused(const float* __restrict__ x,
                                                const float* __restrict__ W,
                                                float* __restrict__ out) {
    __shared__ double cur_s[ROWS_PB];
    const int lane = threadIdx.x;                       // 0..63, one wave
    const long long rowBase = (long long)blockIdx.x * ROWS_PB;

    // W fragment per lane (196 float4 total: 3*64 + 4 tail)
    const float4* __restrict__ W4 = (const float4*)W;
    const float4 w0 = W4[lane];
    const float4 w1 = W4[lane + 64];
    const float4 w2 = W4[lane + 128];
    float4 w3 = make_float4(0.f, 0.f, 0.f, 0.f);
    if (lane < 4) w3 = W4[192 + lane];

    // ---- Phase 1: dot products, one row per wave-iteration ----
    #pragma unroll 4
    for (int r = 0; r < ROWS_PB; ++r) {
        const float4* __restrict__ xr = (const float4*)(x + (rowBase + r) * DIM);
        float4 a0 = xr[lane];
        float4 a1 = xr[lane + 64];
        float4 a2 = xr[lane + 128];
        float4 a3 = make_float4(0.f, 0.f, 0.f, 0.f);
        if (lane < 4) a3 = xr[192 + lane];

        double s = (double)a0.x * (double)w0.x + (double)a0.y * (double)w0.y
                 + (double)a0.z * (double)w0.z + (double)a0.w * (double)w0.w
                 + (double)a1.x * (double)w1.x + (double)a1.y * (double)w1.y
                 + (double)a1.z * (double)w1.z + (double)a1.w * (double)w1.w
                 + (double)a2.x * (double)w2.x + (double)a2.y * (double)w2.y
                 + (double)a2.z * (double)w2.z + (double)a2.w * (double)w2.w
                 + (double)a3.x * (double)w3.x + (double)a3.y * (double)w3.y
                 + (double)a3.z * (double)w3.z + (double)a3.w * (double)w3.w;

        #pragma unroll
        for (int off = 32; off > 0; off >>= 1)
            s += __shfl_down(s, off, 64);
        if (lane == 0) cur_s[r] = s;
    }
    __syncthreads();

    // ---- Phase 2: recurrence, one row per thread ----
    const double cur = cur_s[lane];
    double mem = 0.0;
    float* __restrict__ spkOut = out;
    float* __restrict__ memOut = out + (long long)STEPS * NROWS;
    long long idx = rowBase + lane;

    for (int t = 0; t < STEPS; ++t) {
        const double m = BETA * mem + cur;
        // reset uses PREVIOUS mem: mem_new = (mem_prev > 1) ? 0 : beta*mem_prev+cur
        mem = (mem > 1.0) ? 0.0 : m;
        spkOut[idx] = (mem > 1.0) ? 1.0f : 0.0f;
        memOut[idx] = (float)mem;
        idx += NROWS;
    }
}

extern "C" void kernel_launch(void* const* d_in, const int* in_sizes, int n_in,
                              void* d_out, int out_size, void* d_ws, size_t ws_size,
                              hipStream_t stream) {
    const float* x = (const float*)d_in[0];   // [65536, 784]
    const float* W = (const float*)d_in[1];   // [1, 784]
    float* out = (float*)d_out;               // spk (255*65536) then mem (255*65536)

    dim3 grid(NROWS / ROWS_PB);   // 1024 blocks
    dim3 block(ROWS_PB);          // 64 threads = 1 wave
    hipLaunchKernelGGL(snn_fused, grid, block, 0, stream, x, W, out);
}

// Round 2
// 313.073 us; speedup vs baseline: 1.0672x; 1.0672x over previous
//
#include <hip/hip_runtime.h>

// SNN leaky integrate-and-fire, split into two roofline-shaped kernels.
// x: [65536, 784] f32, W: [1, 784] f32.
// out = concat(spk_rec [255,65536], mem_rec [255,65536]) f32.
//
// K1 (read-bound): one WAVE per row -> 65536 waves (vs 1024 in R1, which was
//     1 wave/SIMD and pure latency). f64 dot + shuffle reduce -> cur in d_ws.
// K2 (write-bound): one thread per row, 255-step f64 recurrence, nontemporal
//     coalesced stores (output never re-read).

#define NROWS   65536
#define DIM     784            // = 196 float4
#define STEPS   255
#define BETA    0.95

// ---- Kernel 1: cur[row] = dot(x[row], W), f64 accumulate ----
__global__ __launch_bounds__(256) void snn_matvec(const float* __restrict__ x,
                                                  const float* __restrict__ W,
                                                  double* __restrict__ cur) {
    const int lane = threadIdx.x & 63;
    const long long row = (long long)blockIdx.x * 4 + (threadIdx.x >> 6);

    const float4* __restrict__ W4 = (const float4*)W;
    const float4* __restrict__ xr = (const float4*)(x + row * DIM);

    // 196 float4 per row: lanes 0..63 take chunks l, l+64, l+128; lanes 0..3 tail.
    float4 a0 = xr[lane];
    float4 a1 = xr[lane + 64];
    float4 a2 = xr[lane + 128];
    float4 w0 = W4[lane];
    float4 w1 = W4[lane + 64];
    float4 w2 = W4[lane + 128];
    float4 a3 = make_float4(0.f, 0.f, 0.f, 0.f);
    float4 w3 = make_float4(0.f, 0.f, 0.f, 0.f);
    if (lane < 4) { a3 = xr[192 + lane]; w3 = W4[192 + lane]; }

    double s = (double)a0.x * (double)w0.x + (double)a0.y * (double)w0.y
             + (double)a0.z * (double)w0.z + (double)a0.w * (double)w0.w
             + (double)a1.x * (double)w1.x + (double)a1.y * (double)w1.y
             + (double)a1.z * (double)w1.z + (double)a1.w * (double)w1.w
             + (double)a2.x * (double)w2.x + (double)a2.y * (double)w2.y
             + (double)a2.z * (double)w2.z + (double)a2.w * (double)w2.w
             + (double)a3.x * (double)w3.x + (double)a3.y * (double)w3.y
             + (double)a3.z * (double)w3.z + (double)a3.w * (double)w3.w;

    #pragma unroll
    for (int off = 32; off > 0; off >>= 1)
        s += __shfl_down(s, off, 64);

    if (lane == 0) cur[row] = s;
}

// ---- Kernel 2: 255-step recurrence, thread per row ----
__global__ __launch_bounds__(256) void snn_recur(const double* __restrict__ curBuf,
                                                 float* __restrict__ out) {
    const long long row = (long long)blockIdx.x * blockDim.x + threadIdx.x;
    const double cur = curBuf[row];
    double mem = 0.0;

    float* __restrict__ spkOut = out + row;
    float* __restrict__ memOut = out + (long long)STEPS * NROWS + row;

    for (int t = 0; t < STEPS; ++t) {
        const double m = BETA * mem + cur;
        // reset uses PREVIOUS mem: mem_new = (mem_prev > 1) ? 0 : beta*mem_prev+cur
        mem = (mem > 1.0) ? 0.0 : m;
        __builtin_nontemporal_store((mem > 1.0) ? 1.0f : 0.0f, spkOut);
        __builtin_nontemporal_store((float)mem, memOut);
        spkOut += NROWS;
        memOut += NROWS;
    }
}

extern "C" void kernel_launch(void* const* d_in, const int* in_sizes, int n_in,
                              void* d_out, int out_size, void* d_ws, size_t ws_size,
                              hipStream_t stream) {
    const float* x = (const float*)d_in[0];   // [65536, 784]
    const float* W = (const float*)d_in[1];   // [1, 784]
    float* out = (float*)d_out;               // spk (255*65536) then mem (255*65536)
    double* cur = (double*)d_ws;              // 65536 * 8 B = 512 KB scratch

    hipLaunchKernelGGL(snn_matvec, dim3(NROWS / 4), dim3(256), 0, stream, x, W, cur);
    hipLaunchKernelGGL(snn_recur, dim3(NROWS / 256), dim3(256), 0, stream, cur, out);
}